// Round 2
// baseline (845.525 us; speedup 1.0000x reference)
//
#include <hip/hip_runtime.h>
#include <hip/hip_bf16.h>

typedef __bf16 bf16;
typedef __attribute__((ext_vector_type(8))) __bf16 bf16x8;
typedef __attribute__((ext_vector_type(4))) float f32x4;

#define E_EDGES 262144
#define MT 128   // rows per block

#define VMW(n)  asm volatile("s_waitcnt vmcnt(" #n ")" ::: "memory")
#define LGKM0   asm volatile("s_waitcnt lgkmcnt(0)" ::: "memory")
#define FENCE   asm volatile("" ::: "memory")
#define BAR     __builtin_amdgcn_s_barrier()

// Pre-pass: transpose + fp32->bf16 convert weights into workspace.
// W1 fp32 [384][512] -> W1t bf16 [512][384];  W2 fp32 [512][128] -> W2t bf16 [128][512]
__global__ void transpose_w(const float* __restrict__ W1, const float* __restrict__ W2,
                            bf16* __restrict__ W1t, bf16* __restrict__ W2t)
{
  int tid = blockIdx.x * 256 + threadIdx.x;
  if (tid < 512 * 384) {
    int n = tid / 384;
    int k = tid - n * 384;
    W1t[tid] = (bf16)W1[k * 512 + n];
  }
  if (tid < 128 * 512) {
    int n = tid >> 9;
    int k = tid & 511;
    W2t[tid] = (bf16)W2[k * 128 + n];
  }
}

__device__ __forceinline__ bf16x8 cvt8v(f32x4 a, f32x4 b) {
  bf16x8 r;
  r[0] = (bf16)a[0]; r[1] = (bf16)a[1]; r[2] = (bf16)a[2]; r[3] = (bf16)a[3];
  r[4] = (bf16)b[0]; r[5] = (bf16)b[1]; r[6] = (bf16)b[2]; r[7] = (bf16)b[3];
  return r;
}

// async global->LDS, 16B per lane; LDS dest is wave-uniform base + lane*16
__device__ __forceinline__ void glds16(const void* g, void* l) {
  __builtin_amdgcn_global_load_lds(
      (const __attribute__((address_space(1))) void*)g,
      (__attribute__((address_space(3))) void*)l,
      16, 0, 0);
}

// Fused: h = silu(concat(x_i,x_j,ea) @ W1 + b1); y = LN(h @ W2 + b2)*g + b + ea
// Schedule: per nc, 16 linearized steps (12 GEMM1-K + 4 GEMM2-s4), depth-2
// staging (step J stages J+2), raw s_barrier + counted vmcnt (never drain 0
// in the loop). B/W2 tiles rotate through 3 LDS buffers; A rotates through
// 2 register sets -> 2 LDS buffers.
__global__ __launch_bounds__(512, 4)
void fused_edge_mlp(const float* __restrict__ x_i,
                    const float* __restrict__ x_j,
                    const float* __restrict__ ea,
                    const bf16* __restrict__ W1t,
                    const float* __restrict__ b1,
                    const bf16* __restrict__ W2t,
                    const float* __restrict__ b2,
                    const float* __restrict__ gmm,
                    const float* __restrict__ bta,
                    float* __restrict__ out)
{
  __shared__ bf16 As[2][128 * 32];    // 16KB  (A tiles, XOR-swizzled)
  __shared__ bf16 Bs[3][128 * 32];    // 24KB  (W1/W2 tiles via glds16, src-swizzled)
  __shared__ bf16 H1s[128 * 136];     // 34.8KB (+8 pad)
  // total 74.8KB -> 2 blocks/CU

  const int t    = threadIdx.x;
  const int w    = t >> 6;             // wave 0..7
  const int lane = t & 63;
  const int l15  = lane & 15;
  const int q    = lane >> 4;          // quad 0..3
  const int srow = t >> 2;             // staging row 0..127 (4 threads/row)
  const int sc   = t & 3;              // staging 16B-block col 0..3
  const int scf  = sc << 3;            // float col offset (0,8,16,24)
  const int swz  = (sc ^ ((srow >> 1) & 3)) << 3;  // swizzled bf16 col (write/src side)
  const int rsw  = (l15 >> 1) & 3;     // read-side swizzle term
  const int wm   = w >> 2;             // GEMM1 row half (64 rows)
  const int wn   = w & 3;              // GEMM1 col quarter (32 cols)
  const long m0  = (long)blockIdx.x * MT;
  const int wb   = (t & ~63) << 3;     // wave-uniform LDS elem base for glds16 (1KB/wave)

  const f32x4 fzero = {0.f, 0.f, 0.f, 0.f};

  // preload b1 for all 4 nc chunks (this thread's 2 columns per chunk)
  float b1r[8];
  #pragma unroll
  for (int j = 0; j < 8; ++j)
    b1r[j] = b1[(j >> 1) * 128 + 32 * wn + 16 * (j & 1) + l15];

  f32x4 acc2[8];                       // C2 [16 x 128] per wave (rows 16w..16w+15)
  #pragma unroll
  for (int i = 0; i < 8; ++i) acc2[i] = fzero;

  f32x4 ar[2][2];                      // A staging registers, 2 rotating sets

  // ---- prologue: stage steps 0 and 1; commit A(0) to LDS ----
  glds16(W1t + (long)srow * 384 + swz, &Bs[0][wb]);              // B(0) -> buf 0
  FENCE;
  {
    const float* p = x_i + (m0 + srow) * 128 + scf;              // A(0) -> set 0
    ar[0][0] = *(const f32x4*)p;  ar[0][1] = *(const f32x4*)(p + 4);
  }
  FENCE;
  glds16(W1t + (long)srow * 384 + 32 + swz, &Bs[1][wb]);         // B(1) -> buf 1
  FENCE;
  {
    const float* p = x_i + (m0 + srow) * 128 + 32 + scf;         // A(1) -> set 1
    ar[1][0] = *(const f32x4*)p;  ar[1][1] = *(const f32x4*)(p + 4);
  }
  FENCE;
  // compiler waits A(0) here -> FIFO also retires B(0)
  *(bf16x8*)&As[0][srow * 32 + swz] = cvt8v(ar[0][0], ar[0][1]);
  LGKM0;
  BAR;

  for (int nc = 0; nc < 4; ++nc) {
    f32x4 acc1[8];                     // C1 [64 x 32] per wave
    #pragma unroll
    for (int i = 0; i < 8; ++i) acc1[i] = fzero;

    #pragma unroll
    for (int j = 0; j < 16; ++j) {
      const int buf  = (nc + j) % 3;       // Bs buffer holding this step's tile
      const int tbuf = (nc + j + 2) % 3;   // Bs buffer being staged

      // ---- stage step j+2 (glds16 first, then A-loads: order matters for FIFO) ----
      {
        const int tt = j + 2;
        if (tt < 12) {
          glds16(W1t + (long)(nc * 128 + srow) * 384 + (tt << 5) + swz, &Bs[tbuf][wb]);
          FENCE;
          const float* s = (tt < 4) ? x_i : (tt < 8) ? x_j : ea;
          const float* p = s + (m0 + srow) * 128 + ((tt & 3) << 5) + scf;
          ar[j & 1][0] = *(const f32x4*)p;  ar[j & 1][1] = *(const f32x4*)(p + 4);
          FENCE;
        } else if (tt < 16) {
          glds16(W2t + (long)srow * 512 + (nc << 7) + ((tt - 12) << 5) + swz, &Bs[tbuf][wb]);
          FENCE;
        } else if (nc < 3) {              // tt=16/17 -> next nc steps 0/1
          glds16(W1t + (long)((nc + 1) * 128 + srow) * 384 + ((tt - 16) << 5) + swz,
                 &Bs[tbuf][wb]);
          FENCE;
          const float* p = x_i + (m0 + srow) * 128 + ((tt - 16) << 5) + scf;
          ar[j & 1][0] = *(const f32x4*)p;  ar[j & 1][1] = *(const f32x4*)(p + 4);
          FENCE;
        }
      }

      // ---- compute step j ----
      if (j < 12) {
        // GEMM1 K-step j: A from As[j&1], B from Bs[buf]
        bf16x8 af[4], bfr[2];
        #pragma unroll
        for (int mi = 0; mi < 4; ++mi)
          af[mi] = *(const bf16x8*)&As[j & 1][(64 * wm + 16 * mi + l15) * 32 + ((q ^ rsw) << 3)];
        #pragma unroll
        for (int ni = 0; ni < 2; ++ni)
          bfr[ni] = *(const bf16x8*)&Bs[buf][(32 * wn + 16 * ni + l15) * 32 + ((q ^ rsw) << 3)];
        __builtin_amdgcn_s_setprio(1);
        #pragma unroll
        for (int mi = 0; mi < 4; ++mi)
          #pragma unroll
          for (int ni = 0; ni < 2; ++ni)
            acc1[mi * 2 + ni] = __builtin_amdgcn_mfma_f32_16x16x32_bf16(
                af[mi], bfr[ni], acc1[mi * 2 + ni], 0, 0, 0);
        __builtin_amdgcn_s_setprio(0);
      } else {
        // GEMM2 s4 = j-12: A from H1s, B (W2 chunk) from Bs[buf]
        const int s4 = j - 12;
        bf16x8 a2 = *(const bf16x8*)&H1s[(16 * w + l15) * 136 + (s4 << 5) + (q << 3)];
        __builtin_amdgcn_s_setprio(1);
        #pragma unroll
        for (int ni = 0; ni < 8; ++ni) {
          bf16x8 b2f = *(const bf16x8*)&Bs[buf][(16 * ni + l15) * 32 + ((q ^ rsw) << 3)];
          acc2[ni] = __builtin_amdgcn_mfma_f32_16x16x32_bf16(a2, b2f, acc2[ni], 0, 0, 0);
        }
        __builtin_amdgcn_s_setprio(0);
      }

      // ---- epilogue of GEMM1 (step 11): bias + SiLU -> H1s ----
      if (j == 11) {
        #pragma unroll
        for (int mi = 0; mi < 4; ++mi)
          #pragma unroll
          for (int ni = 0; ni < 2; ++ni)
            #pragma unroll
            for (int i = 0; i < 4; ++i) {
              float s = acc1[mi * 2 + ni][i] + b1r[(nc << 1) + ni];
              float h = s / (1.f + __expf(-s));
              H1s[(64 * wm + 16 * mi + 4 * q + i) * 136 + 32 * wn + 16 * ni + l15] = (bf16)h;
            }
      }

      // ---- consume A regs (steps whose successor is a GEMM1 step) ----
      if (j <= 10 || (j == 15 && nc < 3)) {
        FENCE;
        // compiler waits A(j+1) regs -> FIFO also retires B(j+1) glds16
        *(bf16x8*)&As[(j + 1) & 1][srow * 32 + swz] =
            cvt8v(ar[(j + 1) & 1][0], ar[(j + 1) & 1][1]);
      }

      // ---- explicit counted waits where no A-consume covers B(j+1) ----
      if (j == 11) VMW(1);   // retire W2 chunk 0; leave chunk-1 glds16 in flight
      if (j == 12) VMW(1);   // retire W2 chunk 1
      if (j == 13) VMW(1);   // retire W2 chunk 2
      if (j == 14) {
        if (nc < 3) VMW(3);  // retire W2 chunk 3; leave B(0'),A(0')x2 in flight
        else        VMW(0);  // last nc: nothing younger
      }

      LGKM0;
      BAR;
    }
  }

  // ---- LN + gamma/beta + residual; wave w owns rows [16w,16w+16) ----
  float b2v[8], gv[8], bv[8];
  #pragma unroll
  for (int ni = 0; ni < 8; ++ni) {
    int n = 16 * ni + l15;
    b2v[ni] = b2[n];
    gv[ni]  = gmm[n];
    bv[ni]  = bta[n];
  }
  #pragma unroll
  for (int ni = 0; ni < 8; ++ni)
    #pragma unroll
    for (int i = 0; i < 4; ++i)
      acc2[ni][i] += b2v[ni];

  #pragma unroll
  for (int i = 0; i < 4; ++i) {
    float s = 0.f, s2 = 0.f;
    #pragma unroll
    for (int ni = 0; ni < 8; ++ni) {
      float v = acc2[ni][i];
      s += v;
      s2 += v * v;
    }
    // reduce across the 16 lanes of this quad (row r=4q+i lives in one quad)
    #pragma unroll
    for (int off = 1; off <= 8; off <<= 1) {
      s  += __shfl_xor(s,  off, 64);
      s2 += __shfl_xor(s2, off, 64);
    }
    float mu   = s * (1.f / 128.f);
    float var  = fmaxf(s2 * (1.f / 128.f) - mu * mu, 0.f);
    float rstd = rsqrtf(var + 1e-5f);
    long  mg   = m0 + 16 * w + 4 * q + i;
    #pragma unroll
    for (int ni = 0; ni < 8; ++ni) {
      int n = 16 * ni + l15;
      float o = (acc2[ni][i] - mu) * rstd * gv[ni] + bv[ni] + ea[mg * 128 + n];
      out[mg * 128 + n] = o;
    }
  }
}

extern "C" void kernel_launch(void* const* d_in, const int* in_sizes, int n_in,
                              void* d_out, int out_size, void* d_ws, size_t ws_size,
                              hipStream_t stream)
{
  const float* x_i = (const float*)d_in[0];
  const float* x_j = (const float*)d_in[1];
  const float* ea  = (const float*)d_in[2];
  const float* W1  = (const float*)d_in[3];
  const float* b1  = (const float*)d_in[4];
  const float* W2  = (const float*)d_in[5];
  const float* b2  = (const float*)d_in[6];
  const float* gm  = (const float*)d_in[7];
  const float* bt  = (const float*)d_in[8];
  float* outp = (float*)d_out;
  bf16* W1t = (bf16*)d_ws;           // 512*384 bf16
  bf16* W2t = W1t + 512 * 384;       // 128*512 bf16

  hipLaunchKernelGGL(transpose_w, dim3(768), dim3(256), 0, stream, W1, W2, W1t, W2t);
  hipLaunchKernelGGL(fused_edge_mlp, dim3(E_EDGES / MT), dim3(512), 0, stream,
                     x_i, x_j, ea, W1t, b1, W2t, b2, gm, bt, outp);
}